// Round 2
// baseline (4269.943 us; speedup 1.0000x reference)
//
#include <hip/hip_runtime.h>
#include <hip/hip_bf16.h>
#include <stdint.h>

#define BATCH 256
#define SEQT  512
#define INSZ  256
#define HID   512

typedef __attribute__((ext_vector_type(8))) short short8;
typedef __attribute__((ext_vector_type(4))) float floatx4;
typedef __attribute__((ext_vector_type(4))) float float4v;

__device__ __forceinline__ ushort f2b(float f) {
    union { float f; uint i; } v; v.f = f;
    uint r = (v.i + 0x7FFFu + ((v.i >> 16) & 1u)) >> 16;
    return (ushort)r;
}
__device__ __forceinline__ float fsigmoid(float x) {
    float e = __builtin_amdgcn_exp2f(-1.44269504f * x);
    return __builtin_amdgcn_rcpf(1.0f + e);
}
__device__ __forceinline__ float ftanh(float x) {
    float e = __builtin_amdgcn_exp2f(-2.88539008f * x);
    return 2.0f * __builtin_amdgcn_rcpf(1.0f + e) - 1.0f;
}

// Convert x fp32 -> bf16, same [B][T][I] layout. 4 elements/thread.
__global__ __launch_bounds__(256) void pack_x(
    const float4v* __restrict__ x, ushort* __restrict__ xp)
{
    uint idx = blockIdx.x * 256u + threadIdx.x;   // up to 8388608
    float4v v = x[idx];
    ushort4 o;
    o.x = f2b(v[0]); o.y = f2b(v[1]); o.z = f2b(v[2]); o.w = f2b(v[3]);
    *(ushort4*)&xp[idx * 4u] = o;
}

// Pack the 8 fp32 weight matrices into bf16 MFMA B-fragment layout.
// Wh per gate q: [c16(32)][k8(64)][n(16)][j(8)]  value = W[k8*8+j][c16*16+n]
// Wu per gate q: [c16(32)][k8(32)][n(16)][j(8)]
// Thread mapping keeps n fastest for coalesced fp32 reads.
__global__ __launch_bounds__(256) void pack_weights(
    const float* __restrict__ whi, const float* __restrict__ whf,
    const float* __restrict__ whg, const float* __restrict__ who,
    const float* __restrict__ wui, const float* __restrict__ wuf,
    const float* __restrict__ wug, const float* __restrict__ wuo,
    ushort* __restrict__ whp, ushort* __restrict__ wup)
{
    uint idx = blockIdx.x * 256u + threadIdx.x;
    if (idx < (1u << 20)) {
        // idx = ((q*32 + c16)*64 + k8)*128 + j*16 + n
        uint n = idx & 15u, j = (idx >> 4) & 7u;
        uint k8 = (idx >> 7) & 63u, c16 = (idx >> 13) & 31u, q = idx >> 18;
        const float* w = (q == 0) ? whi : (q == 1) ? whf : (q == 2) ? whg : who;
        float v = w[(k8 * 8u + j) * HID + c16 * 16u + n];
        whp[(((q * 32u + c16) * 64u + k8) * 16u + n) * 8u + j] = f2b(v);
    } else {
        uint idx2 = idx - (1u << 20);
        if (idx2 < (1u << 19)) {
            uint n = idx2 & 15u, j = (idx2 >> 4) & 7u;
            uint k8 = (idx2 >> 7) & 31u, c16 = (idx2 >> 12) & 31u, q = idx2 >> 17;
            const float* w = (q == 0) ? wui : (q == 1) ? wuf : (q == 2) ? wug : wuo;
            float v = w[(k8 * 8u + j) * HID + c16 * 16u + n];
            wup[(((q * 32u + c16) * 32u + k8) * 16u + n) * 8u + j] = f2b(v);
        }
    }
}

// One time step: gates = h_t @ W_h + x_t @ W_u + b ; LSTM elementwise ; write h_{t+1}.
// Grid: 256 blocks = 16 batch-groups (16 rows) x 16 unit-groups (32 units).
// Block: 4 waves = (usub: 2 unit subtiles of 16) x (ksub: 2-way K split of 24 k-iters).
__global__ __launch_bounds__(256) void lstm_step(
    const short8* __restrict__ xp,   // [B][T][I] bf16 as short8
    const short8* __restrict__ whp,  // packed, q-stride 32768 (short8)
    const short8* __restrict__ wup,  // packed, q-stride 16384 (short8)
    const float* __restrict__ bi, const float* __restrict__ bfr,
    const float* __restrict__ bg, const float* __restrict__ bo,
    const short8* __restrict__ hin,  // hp layout [k8(64)][b(256)] short8
    ushort* __restrict__ hout,
    float* __restrict__ cst,         // [H][B] fp32
    float* __restrict__ out, int t)
{
    __shared__ float red[2][64][16];

    uint blk = blockIdx.x;
    uint rg = blk >> 4, ug = blk & 15u;
    uint bbase = rg * 16u;
    uint wave = threadIdx.x >> 6, lane = threadIdx.x & 63u;
    uint usub = wave & 1u, ksub = wave >> 1;
    uint m = lane & 15u, quad = lane >> 4;
    uint c16 = ug * 2u + usub;
    uint b_row = bbase + m;

    floatx4 acc[4] = {};

    uint it0 = ksub * 12u, it1 = it0 + 12u;
    for (uint it = it0; it < it1; ++it) {
        short8 a;
        short8 bf0, bf1, bf2, bf3;
        if (it < 16u) {
            uint k8 = it * 4u + quad;
            a = hin[k8 * BATCH + b_row];
            uint base = (c16 * 64u + k8) * 16u + m;
            bf0 = whp[base];
            bf1 = whp[32768u + base];
            bf2 = whp[65536u + base];
            bf3 = whp[98304u + base];
        } else {
            uint kx = it - 16u;
            a = xp[(b_row * SEQT + (uint)t) * 32u + kx * 4u + quad];
            uint base = (c16 * 32u + kx * 4u + quad) * 16u + m;
            bf0 = wup[base];
            bf1 = wup[16384u + base];
            bf2 = wup[32768u + base];
            bf3 = wup[49152u + base];
        }
        acc[0] = __builtin_amdgcn_mfma_f32_16x16x32_bf16(a, bf0, acc[0], 0, 0, 0);
        acc[1] = __builtin_amdgcn_mfma_f32_16x16x32_bf16(a, bf1, acc[1], 0, 0, 0);
        acc[2] = __builtin_amdgcn_mfma_f32_16x16x32_bf16(a, bf2, acc[2], 0, 0, 0);
        acc[3] = __builtin_amdgcn_mfma_f32_16x16x32_bf16(a, bf3, acc[3], 0, 0, 0);
    }

    if (ksub == 1u) {
        #pragma unroll
        for (int q = 0; q < 4; ++q)
            *(floatx4*)&red[usub][lane][q * 4] = acc[q];
    }
    __syncthreads();
    if (ksub == 0u) {
        #pragma unroll
        for (int q = 0; q < 4; ++q) {
            floatx4 o = *(floatx4*)&red[usub][lane][q * 4];
            acc[q][0] += o[0]; acc[q][1] += o[1];
            acc[q][2] += o[2]; acc[q][3] += o[3];
        }
        uint j = c16 * 16u + m;
        float vbi = bi[j];
        float vbf = bfr[j];
        float vbg = bg[j];
        float vbo = bo[j];
        uint brow0 = bbase + quad * 4u;
        floatx4 cold = *(floatx4*)&cst[j * BATCH + brow0];
        floatx4 cnew;
        uint hbase = (j >> 3) * BATCH;  // k8 * B
        uint j7 = j & 7u;
        #pragma unroll
        for (int r = 0; r < 4; ++r) {
            float gi = fsigmoid(acc[0][r] + vbi);
            float gf = fsigmoid(acc[1][r] + vbf);
            float gg = ftanh(acc[2][r] + vbg);
            float go = fsigmoid(acc[3][r] + vbo);
            float cn = gf * cold[r] + gi * gg;
            cnew[r] = cn;
            float hv = go * ftanh(cn);
            hout[(hbase + brow0 + r) * 8u + j7] = f2b(hv);
            if (t == SEQT - 1) out[(brow0 + r) * HID + j] = hv;
        }
        *(floatx4*)&cst[j * BATCH + brow0] = cnew;
    }
}

extern "C" void kernel_launch(void* const* d_in, const int* in_sizes, int n_in,
                              void* d_out, int out_size, void* d_ws, size_t ws_size,
                              hipStream_t stream)
{
    (void)in_sizes; (void)n_in; (void)out_size; (void)ws_size;

    const float* x   = (const float*)d_in[0];
    const float* wui = (const float*)d_in[1];
    const float* whi = (const float*)d_in[2];
    const float* bi  = (const float*)d_in[3];
    const float* wuf = (const float*)d_in[4];
    const float* whf = (const float*)d_in[5];
    const float* bfr = (const float*)d_in[6];
    const float* wug = (const float*)d_in[7];
    const float* whg = (const float*)d_in[8];
    const float* bg  = (const float*)d_in[9];
    const float* wuo = (const float*)d_in[10];
    const float* who = (const float*)d_in[11];
    const float* bo  = (const float*)d_in[12];

    char* ws = (char*)d_ws;
    ushort* hp0 = (ushort*)(ws);              // 256 KB  (h packed, buf 0)
    ushort* hp1 = (ushort*)(ws + 262144);     // 256 KB  (h packed, buf 1)
    float*  cst = (float*)(ws + 524288);      // 512 KB  c state [H][B] fp32
    ushort* whp = (ushort*)(ws + 1048576);    // 2 MB    packed W_h bf16
    ushort* wup = (ushort*)(ws + 3145728);    // 1 MB    packed W_u bf16
    ushort* xp  = (ushort*)(ws + 4194304);    // 64 MB   x bf16

    hipMemsetAsync(hp0, 0, 262144, stream);
    hipMemsetAsync(cst, 0, 524288, stream);
    pack_x<<<32768, 256, 0, stream>>>((const float4v*)x, xp);
    pack_weights<<<6144, 256, 0, stream>>>(whi, whf, whg, who,
                                           wui, wuf, wug, wuo, whp, wup);

    ushort* hbuf[2] = {hp0, hp1};
    for (int t = 0; t < SEQT; ++t) {
        lstm_step<<<256, 256, 0, stream>>>(
            (const short8*)xp, (const short8*)whp, (const short8*)wup,
            bi, bfr, bg, bo,
            (const short8*)hbuf[t & 1], hbuf[(t + 1) & 1],
            cst, (float*)d_out, t);
    }
}